// Round 1
// baseline (157.546 us; speedup 1.0000x reference)
//
#include <hip/hip_runtime.h>
#include <stdint.h>

// MetricLoss: B=1024, M=32, F=256, K_GRP=4
// out[0] = (1/1536) * sum_{same-group pairs i<j, m} ||x_i,m - x_j,m||^2
// out[1] = (1/522240) * sum_{g_i<g_j, m} relu(1 - ||x_i,m - x_j,m||^2)
//
// ws layout:
//   [0,        16 MiB)  : xb  bf16 [32][1024][256]  (per-m contiguous matrices)
//   [16 MiB,  +128 KiB) : sq  f32  [32][1024]
//   [+8 B]              : accum[2] f32 {homo_sum, heter_sum}
// needs ws_size >= ~16.2 MiB

typedef __attribute__((ext_vector_type(4))) float f32x4;
typedef __attribute__((ext_vector_type(8))) short bf16x8;

#define XB_OFF   0
#define SQ_OFF   16777216u
#define ACC_OFF  16908288u

#define AS1 __attribute__((address_space(1)))
#define AS3 __attribute__((address_space(3)))

__device__ __forceinline__ void async16(const void* g, void* l) {
  __builtin_amdgcn_global_load_lds((const AS1 unsigned int*)(uintptr_t)g,
                                   (AS3 unsigned int*)(uintptr_t)l, 16, 0, 0);
}

__device__ __forceinline__ unsigned short f2bf(float f) {
  union { float f; unsigned u; } v; v.f = f;
  return (unsigned short)((v.u + 0x7fffu + ((v.u >> 16) & 1u)) >> 16);
}

// ---- Kernel 1: convert x[i][m][f] fp32 -> xb[m][i][f] bf16; sq[m][i] = ||row||^2
__global__ __launch_bounds__(256) void k_convert(const float* __restrict__ x,
                                                 unsigned short* __restrict__ xb,
                                                 float* __restrict__ sq) {
  const int task = blockIdx.x * 4 + (threadIdx.x >> 6);  // task = i*32 + m, 32768 tasks
  const int lane = threadIdx.x & 63;
  const int i = task >> 5;
  const int m = task & 31;
  const float4 v = *(const float4*)(x + (size_t)task * 256 + lane * 4);
  float s = v.x * v.x + v.y * v.y + v.z * v.z + v.w * v.w;
  #pragma unroll
  for (int off = 32; off; off >>= 1) s += __shfl_xor(s, off, 64);
  if (lane == 0) sq[m * 1024 + i] = s;
  ushort4 o;
  o.x = f2bf(v.x); o.y = f2bf(v.y); o.z = f2bf(v.z); o.w = f2bf(v.w);
  *(ushort4*)(xb + ((size_t)(m * 1024 + i)) * 256 + lane * 4) = o;
}

// ---- Kernel 2: homo loss via  sum_{a<b}||xa-xb||^2 = 4*sum sq_a - ||sum xa||^2
__global__ __launch_bounds__(256) void k_homo(const float* __restrict__ x,
                                              const float* __restrict__ sq,
                                              float* __restrict__ accum) {
  const int task = blockIdx.x * 4 + (threadIdx.x >> 6);  // task = g*32 + m, 8192 tasks
  const int lane = threadIdx.x & 63;
  const int g = task >> 5;
  const int m = task & 31;
  const float* base = x + ((size_t)(g * 4) * 32 + m) * 256 + lane * 4;
  const float4 a = *(const float4*)(base);
  const float4 b = *(const float4*)(base + 8192);
  const float4 c = *(const float4*)(base + 16384);
  const float4 d = *(const float4*)(base + 24576);
  const float sx = a.x + b.x + c.x + d.x;
  const float sy = a.y + b.y + c.y + d.y;
  const float sz = a.z + b.z + c.z + d.z;
  const float sw = a.w + b.w + c.w + d.w;
  float s = sx * sx + sy * sy + sz * sz + sw * sw;
  #pragma unroll
  for (int off = 32; off; off >>= 1) s += __shfl_xor(s, off, 64);
  if (lane == 0) {
    const float* q = sq + m * 1024 + g * 4;
    const float contrib = 4.f * (q[0] + q[1] + q[2] + q[3]) - s;
    atomicAdd(&accum[0], contrib);
  }
}

// ---- Kernel 3: heter loss. Batched Gram per m, upper-triangular 128x128 tiles.
__global__ __launch_bounds__(256) void k_heter(const unsigned short* __restrict__ xb,
                                               const float* __restrict__ sq,
                                               float* __restrict__ accum) {
  const int m = blockIdx.y;
  int t = blockIdx.x, r = 0;           // 36 tiles: (r,c) with c>=r, 8x8 blocks of 128
  while (t >= 8 - r) { t -= 8 - r; ++r; }
  const int cb = r + t;

  __shared__ __align__(16) unsigned short ldsA[128 * 32];
  __shared__ __align__(16) unsigned short ldsB[128 * 32];
  __shared__ float part[4];

  const int tid = threadIdx.x;
  const int lane = tid & 63;
  const int wid = tid >> 6;
  const int wr = wid >> 1, wc = wid & 1;   // 2x2 waves, each 64x64 output

  const unsigned short* Xa = xb + ((size_t)m * 1024 + r  * 128) * 256;
  const unsigned short* Xb = xb + ((size_t)m * 1024 + cb * 128) * 256;

  // staging map: thread t covers tile-row t>>2 (then +64), 16B chunk t&3
  const int srow = tid >> 2;
  const int sch  = tid & 3;
  const size_t goff0 = (size_t)srow * 256 + sch * 8;
  const size_t goff1 = (size_t)(srow + 64) * 256 + sch * 8;

  f32x4 acc[4][4] = {};

  const int fr = lane & 15;   // fragment row/col within 16
  const int kg = lane >> 4;   // k-group (8 contiguous k per lane)

  for (int kt = 0; kt < 8; ++kt) {
    const int k0 = kt * 32;
    async16(Xa + goff0 + k0, (char*)ldsA + tid * 16);
    async16(Xa + goff1 + k0, (char*)ldsA + 4096 + tid * 16);
    async16(Xb + goff0 + k0, (char*)ldsB + tid * 16);
    async16(Xb + goff1 + k0, (char*)ldsB + 4096 + tid * 16);
    __syncthreads();   // compiler emits vmcnt(0) before s_barrier
    bf16x8 af[4], bfr[4];
    #pragma unroll
    for (int q = 0; q < 4; ++q) {
      af[q]  = *(const bf16x8*)(ldsA + (wr * 64 + q * 16 + fr) * 32 + kg * 8);
      bfr[q] = *(const bf16x8*)(ldsB + (wc * 64 + q * 16 + fr) * 32 + kg * 8);
    }
    #pragma unroll
    for (int ai = 0; ai < 4; ++ai)
      #pragma unroll
      for (int bj = 0; bj < 4; ++bj)
        acc[ai][bj] = __builtin_amdgcn_mfma_f32_16x16x32_bf16(af[ai], bfr[bj],
                                                              acc[ai][bj], 0, 0, 0);
    __syncthreads();
  }

  // epilogue: relu(1 - (sq_i + sq_j - 2*dot)), strict group mask, reduce
  const int ibase = r  * 128 + wr * 64;
  const int jbase = cb * 128 + wc * 64;
  const float* sqm = sq + m * 1024;

  float sqi[4][4];
  #pragma unroll
  for (int ai = 0; ai < 4; ++ai)
    #pragma unroll
    for (int rg = 0; rg < 4; ++rg)
      sqi[ai][rg] = sqm[ibase + ai * 16 + kg * 4 + rg];

  float local = 0.f;
  #pragma unroll
  for (int bj = 0; bj < 4; ++bj) {
    const int j = jbase + bj * 16 + fr;       // C/D: col = lane&15
    const float sqj = sqm[j];
    const int gj = j >> 2;
    #pragma unroll
    for (int ai = 0; ai < 4; ++ai) {
      #pragma unroll
      for (int rg = 0; rg < 4; ++rg) {
        const int i = ibase + ai * 16 + kg * 4 + rg;  // C/D: row = (lane>>4)*4 + reg
        const float d = sqi[ai][rg] + sqj - 2.f * acc[ai][bj][rg];
        const float v = 1.f - d;
        if (v > 0.f && gj > (i >> 2)) local += v;
      }
    }
  }
  #pragma unroll
  for (int off = 32; off; off >>= 1) local += __shfl_xor(local, off, 64);
  if (lane == 0) part[wid] = local;
  __syncthreads();
  if (tid == 0) atomicAdd(&accum[1], part[0] + part[1] + part[2] + part[3]);
}

// ---- Kernel 4: final scaling
__global__ void k_final(const float* __restrict__ accum, float* __restrict__ out) {
  out[0] = accum[0] * (1.0f / 1536.0f);    // 2/(B*(k-1))
  out[1] = accum[1] * (1.0f / 522240.0f);  // 2/(B*(B-k))
}

extern "C" void kernel_launch(void* const* d_in, const int* in_sizes, int n_in,
                              void* d_out, int out_size, void* d_ws, size_t ws_size,
                              hipStream_t stream) {
  const float* x = (const float*)d_in[0];
  float* out = (float*)d_out;
  char* ws = (char*)d_ws;
  unsigned short* xb = (unsigned short*)(ws + XB_OFF);
  float* sq    = (float*)(ws + SQ_OFF);
  float* accum = (float*)(ws + ACC_OFF);

  hipMemsetAsync(accum, 0, 2 * sizeof(float), stream);
  k_convert<<<8192, 256, 0, stream>>>(x, xb, sq);
  k_homo<<<2048, 256, 0, stream>>>(x, sq, accum);
  k_heter<<<dim3(36, 32), 256, 0, stream>>>(xb, sq, accum);
  k_final<<<1, 1, 0, stream>>>(accum, out);
}

// Round 2
// 47.907 us; speedup vs baseline: 3.2886x; 3.2886x over previous
//
#include <hip/hip_runtime.h>
#include <stdint.h>

// MetricLoss: B=1024, M=32, F=256, K_GRP=4
// out[0] = (1/1536) * sum_{same-group pairs i<j, m} ||x_i,m - x_j,m||^2
// out[1] = (1/522240) * sum_{g_i<g_j, m} relu(1 - ||x_i,m - x_j,m||^2)
//
// ws layout:
//   [0,        16 MiB)   : xb  bf16 [32][1024][256]  (per-m contiguous matrices)
//   [16 MiB,  +128 KiB)  : sq  f32  [32][1024]
//   [+32 KiB]            : homo_part  f32 [8192]   (per-(g,m) partials)
//   [+4.5 KiB]           : heter_part f32 [1152]   (per-block partials)

typedef __attribute__((ext_vector_type(4))) float f32x4;
typedef __attribute__((ext_vector_type(8))) short bf16x8;

#define XB_OFF    0u
#define SQ_OFF    16777216u
#define HOMO_OFF  16908288u   // 8192 floats
#define HETER_OFF 16941056u   // 1152 floats

#define AS1 __attribute__((address_space(1)))
#define AS3 __attribute__((address_space(3)))

__device__ __forceinline__ void async16(const void* g, void* l) {
  __builtin_amdgcn_global_load_lds((const AS1 unsigned int*)(uintptr_t)g,
                                   (AS3 unsigned int*)(uintptr_t)l, 16, 0, 0);
}

__device__ __forceinline__ unsigned short f2bf(float f) {
  union { float f; unsigned u; } v; v.f = f;
  return (unsigned short)((v.u + 0x7fffu + ((v.u >> 16) & 1u)) >> 16);
}

// ---- Kernel 1 (fused convert + homo):
// one wave per (g, m): reads the 4 group rows of x once, writes bf16 + sq,
// and computes  sum_{a<b}||xa-xb||^2 = 4*sum||xa||^2 - ||sum xa||^2  in fp32.
__global__ __launch_bounds__(256) void k_fused(const float* __restrict__ x,
                                               unsigned short* __restrict__ xb,
                                               float* __restrict__ sq,
                                               float* __restrict__ homo_part) {
  const int task = blockIdx.x * 4 + (threadIdx.x >> 6);  // task = g*32 + m, 8192 tasks
  const int lane = threadIdx.x & 63;
  const int g = task >> 5;
  const int m = task & 31;

  const float* base = x + ((size_t)(g * 4) * 32 + m) * 256 + lane * 4;  // row stride 32*256
  float4 v[4];
  float sqv[4];
  #pragma unroll
  for (int a = 0; a < 4; ++a) {
    v[a] = *(const float4*)(base + a * 8192);
    float s = v[a].x * v[a].x + v[a].y * v[a].y + v[a].z * v[a].z + v[a].w * v[a].w;
    #pragma unroll
    for (int off = 32; off; off >>= 1) s += __shfl_xor(s, off, 64);
    sqv[a] = s;
    const int i = g * 4 + a;
    if (lane == 0) sq[m * 1024 + i] = s;
    ushort4 o;
    o.x = f2bf(v[a].x); o.y = f2bf(v[a].y); o.z = f2bf(v[a].z); o.w = f2bf(v[a].w);
    *(ushort4*)(xb + ((size_t)(m * 1024 + i)) * 256 + lane * 4) = o;
  }
  const float sx = v[0].x + v[1].x + v[2].x + v[3].x;
  const float sy = v[0].y + v[1].y + v[2].y + v[3].y;
  const float sz = v[0].z + v[1].z + v[2].z + v[3].z;
  const float sw = v[0].w + v[1].w + v[2].w + v[3].w;
  float s = sx * sx + sy * sy + sz * sz + sw * sw;
  #pragma unroll
  for (int off = 32; off; off >>= 1) s += __shfl_xor(s, off, 64);
  if (lane == 0)
    homo_part[task] = 4.f * (sqv[0] + sqv[1] + sqv[2] + sqv[3]) - s;
}

// ---- Kernel 2: heter loss. Batched Gram per m, upper-triangular 128x128 tiles.
__global__ __launch_bounds__(256) void k_heter(const unsigned short* __restrict__ xb,
                                               const float* __restrict__ sq,
                                               float* __restrict__ heter_part) {
  const int m = blockIdx.y;
  int t = blockIdx.x, r = 0;           // 36 tiles: (r,c) with c>=r, 8x8 blocks of 128
  while (t >= 8 - r) { t -= 8 - r; ++r; }
  const int cb = r + t;

  __shared__ __align__(16) unsigned short ldsA[128 * 32];
  __shared__ __align__(16) unsigned short ldsB[128 * 32];
  __shared__ float part[4];

  const int tid = threadIdx.x;
  const int lane = tid & 63;
  const int wid = tid >> 6;
  const int wr = wid >> 1, wc = wid & 1;   // 2x2 waves, each 64x64 output

  const unsigned short* Xa = xb + ((size_t)m * 1024 + r  * 128) * 256;
  const unsigned short* Xb = xb + ((size_t)m * 1024 + cb * 128) * 256;

  // staging map: thread t covers tile-row t>>2 (then +64), 16B chunk t&3
  const int srow = tid >> 2;
  const int sch  = tid & 3;
  const size_t goff0 = (size_t)srow * 256 + sch * 8;
  const size_t goff1 = (size_t)(srow + 64) * 256 + sch * 8;

  f32x4 acc[4][4] = {};

  const int fr = lane & 15;   // fragment row/col within 16
  const int kg = lane >> 4;   // k-group (8 contiguous k per lane)

  for (int kt = 0; kt < 8; ++kt) {
    const int k0 = kt * 32;
    async16(Xa + goff0 + k0, (char*)ldsA + tid * 16);
    async16(Xa + goff1 + k0, (char*)ldsA + 4096 + tid * 16);
    async16(Xb + goff0 + k0, (char*)ldsB + tid * 16);
    async16(Xb + goff1 + k0, (char*)ldsB + 4096 + tid * 16);
    __syncthreads();   // compiler emits vmcnt(0) before s_barrier
    bf16x8 af[4], bfr[4];
    #pragma unroll
    for (int q = 0; q < 4; ++q) {
      af[q]  = *(const bf16x8*)(ldsA + (wr * 64 + q * 16 + fr) * 32 + kg * 8);
      bfr[q] = *(const bf16x8*)(ldsB + (wc * 64 + q * 16 + fr) * 32 + kg * 8);
    }
    #pragma unroll
    for (int ai = 0; ai < 4; ++ai)
      #pragma unroll
      for (int bj = 0; bj < 4; ++bj)
        acc[ai][bj] = __builtin_amdgcn_mfma_f32_16x16x32_bf16(af[ai], bfr[bj],
                                                              acc[ai][bj], 0, 0, 0);
    __syncthreads();
  }

  // epilogue: relu(1 - (sq_i + sq_j - 2*dot)), strict group mask, reduce
  const int ibase = r  * 128 + wr * 64;
  const int jbase = cb * 128 + wc * 64;
  const float* sqm = sq + m * 1024;

  float sqi[4][4];
  #pragma unroll
  for (int ai = 0; ai < 4; ++ai)
    #pragma unroll
    for (int rg = 0; rg < 4; ++rg)
      sqi[ai][rg] = sqm[ibase + ai * 16 + kg * 4 + rg];

  float local = 0.f;
  #pragma unroll
  for (int bj = 0; bj < 4; ++bj) {
    const int j = jbase + bj * 16 + fr;       // C/D: col = lane&15
    const float sqj = sqm[j];
    const int gj = j >> 2;
    #pragma unroll
    for (int ai = 0; ai < 4; ++ai) {
      #pragma unroll
      for (int rg = 0; rg < 4; ++rg) {
        const int i = ibase + ai * 16 + kg * 4 + rg;  // C/D: row = (lane>>4)*4 + reg
        const float d = sqi[ai][rg] + sqj - 2.f * acc[ai][bj][rg];
        const float v = 1.f - d;
        if (v > 0.f && gj > (i >> 2)) local += v;
      }
    }
  }
  #pragma unroll
  for (int off = 32; off; off >>= 1) local += __shfl_xor(local, off, 64);
  if (lane == 0) part[wid] = local;
  __syncthreads();
  if (tid == 0)
    heter_part[m * 36 + blockIdx.x] = part[0] + part[1] + part[2] + part[3];
}

// ---- Kernel 3: final reduction of partials + scaling (single block)
__global__ __launch_bounds__(256) void k_final(const float* __restrict__ homo_part,
                                               const float* __restrict__ heter_part,
                                               float* __restrict__ out) {
  __shared__ float red[8];
  const int tid = threadIdx.x;
  const int lane = tid & 63;
  const int wid = tid >> 6;

  float h = 0.f;
  for (int i = tid; i < 8192; i += 256) h += homo_part[i];
  #pragma unroll
  for (int off = 32; off; off >>= 1) h += __shfl_xor(h, off, 64);
  if (lane == 0) red[wid] = h;

  float e = 0.f;
  for (int i = tid; i < 1152; i += 256) e += heter_part[i];
  #pragma unroll
  for (int off = 32; off; off >>= 1) e += __shfl_xor(e, off, 64);
  if (lane == 0) red[4 + wid] = e;

  __syncthreads();
  if (tid == 0) out[0] = (red[0] + red[1] + red[2] + red[3]) * (1.0f / 1536.0f);
  if (tid == 1) out[1] = (red[4] + red[5] + red[6] + red[7]) * (1.0f / 522240.0f);
}

extern "C" void kernel_launch(void* const* d_in, const int* in_sizes, int n_in,
                              void* d_out, int out_size, void* d_ws, size_t ws_size,
                              hipStream_t stream) {
  const float* x = (const float*)d_in[0];
  float* out = (float*)d_out;
  char* ws = (char*)d_ws;
  unsigned short* xb = (unsigned short*)(ws + XB_OFF);
  float* sq         = (float*)(ws + SQ_OFF);
  float* homo_part  = (float*)(ws + HOMO_OFF);
  float* heter_part = (float*)(ws + HETER_OFF);

  k_fused<<<2048, 256, 0, stream>>>(x, xb, sq, homo_part);
  k_heter<<<dim3(36, 32), 256, 0, stream>>>(xb, sq, heter_part);
  k_final<<<1, 256, 0, stream>>>(homo_part, heter_part, out);
}

// Round 3
// 47.581 us; speedup vs baseline: 3.3111x; 1.0068x over previous
//
#include <hip/hip_runtime.h>
#include <stdint.h>

// MetricLoss: B=1024, M=32, F=256, K_GRP=4
// out[0] = (1/1536) * sum_{same-group pairs i<j, m} ||x_i,m - x_j,m||^2
// out[1] = (1/522240) * sum_{g_i<g_j, m} relu(1 - ||x_i,m - x_j,m||^2)
//
// ws layout:
//   [0,        16 MiB)   : xb  bf16 [32][1024][256]  (per-m contiguous matrices)
//   [16 MiB,  +128 KiB)  : sq  f32  [32][1024]
//   [+32 KiB]            : homo_part  f32 [8192]
//   [+4.5 KiB]           : heter_part f32 [1152]

typedef __attribute__((ext_vector_type(4))) float f32x4;
typedef __attribute__((ext_vector_type(8))) short bf16x8;

#define XB_OFF    0u
#define SQ_OFF    16777216u
#define HOMO_OFF  16908288u   // 8192 floats
#define HETER_OFF 16941056u   // 1152 floats

#define AS1 __attribute__((address_space(1)))
#define AS3 __attribute__((address_space(3)))

__device__ __forceinline__ void async16(const void* g, void* l) {
  __builtin_amdgcn_global_load_lds((const AS1 unsigned int*)(uintptr_t)g,
                                   (AS3 unsigned int*)(uintptr_t)l, 16, 0, 0);
}

__device__ __forceinline__ unsigned short f2bf(float f) {
  union { float f; unsigned u; } v; v.f = f;
  return (unsigned short)((v.u + 0x7fffu + ((v.u >> 16) & 1u)) >> 16);
}

// ---- Kernel 1 (fused convert + homo):
// one wave per (g, m): reads the 4 group rows of x once, writes bf16 + sq,
// and computes  sum_{a<b}||xa-xb||^2 = 4*sum||xa||^2 - ||sum xa||^2  in fp32.
__global__ __launch_bounds__(256) void k_fused(const float* __restrict__ x,
                                               unsigned short* __restrict__ xb,
                                               float* __restrict__ sq,
                                               float* __restrict__ homo_part) {
  const int task = blockIdx.x * 4 + (threadIdx.x >> 6);  // task = g*32 + m, 8192 tasks
  const int lane = threadIdx.x & 63;
  const int g = task >> 5;
  const int m = task & 31;

  const float* base = x + ((size_t)(g * 4) * 32 + m) * 256 + lane * 4;  // row stride 32*256
  float4 v[4];
  float sqv[4];
  #pragma unroll
  for (int a = 0; a < 4; ++a) {
    v[a] = *(const float4*)(base + a * 8192);
    float s = v[a].x * v[a].x + v[a].y * v[a].y + v[a].z * v[a].z + v[a].w * v[a].w;
    #pragma unroll
    for (int off = 32; off; off >>= 1) s += __shfl_xor(s, off, 64);
    sqv[a] = s;
    const int i = g * 4 + a;
    if (lane == 0) sq[m * 1024 + i] = s;
    ushort4 o;
    o.x = f2bf(v[a].x); o.y = f2bf(v[a].y); o.z = f2bf(v[a].z); o.w = f2bf(v[a].w);
    *(ushort4*)(xb + ((size_t)(m * 1024 + i)) * 256 + lane * 4) = o;
  }
  const float sx = v[0].x + v[1].x + v[2].x + v[3].x;
  const float sy = v[0].y + v[1].y + v[2].y + v[3].y;
  const float sz = v[0].z + v[1].z + v[2].z + v[3].z;
  const float sw = v[0].w + v[1].w + v[2].w + v[3].w;
  float s = sx * sx + sy * sy + sz * sz + sw * sw;
  #pragma unroll
  for (int off = 32; off; off >>= 1) s += __shfl_xor(s, off, 64);
  if (lane == 0)
    homo_part[task] = 4.f * (sqv[0] + sqv[1] + sqv[2] + sqv[3]) - s;
}

// ---- Kernel 2: heter loss. Batched Gram per m, upper-triangular 128x128 tiles.
// LDS tiles [128][32] bf16 with 16B-chunk XOR swizzle (T2, both-sides: linear
// gload_lds dest + pre-swizzled global source chunk + swizzled ds_read chunk).
// Unswizzled, lanes 0-15 of a fragment read hit 2 bank-quads -> 8-way conflict.
__global__ __launch_bounds__(256) void k_heter(const unsigned short* __restrict__ xb,
                                               const float* __restrict__ sq,
                                               float* __restrict__ heter_part) {
  const int m = blockIdx.y;
  int t = blockIdx.x, r = 0;           // 36 tiles: (r,c) with c>=r, 8x8 blocks of 128
  while (t >= 8 - r) { t -= 8 - r; ++r; }
  const int cb = r + t;

  __shared__ __align__(16) unsigned short ldsA[128 * 32];
  __shared__ __align__(16) unsigned short ldsB[128 * 32];
  __shared__ float part[4];

  const int tid = threadIdx.x;
  const int lane = tid & 63;
  const int wid = tid >> 6;
  const int wr = wid >> 1, wc = wid & 1;   // 2x2 waves, each 64x64 output

  const unsigned short* Xa = xb + ((size_t)m * 1024 + r  * 128) * 256;
  const unsigned short* Xb = xb + ((size_t)m * 1024 + cb * 128) * 256;

  // staging map: thread t covers tile-row t>>2 (then +64), LDS 16B chunk t&3.
  // swizzle: LDS chunk c of row holds GLOBAL chunk c ^ ((row>>1)&3).
  const int srow = tid >> 2;
  const int key_s = (srow >> 1) & 3;              // same for srow and srow+64
  const int gch  = (tid & 3) ^ key_s;
  const size_t goff0 = (size_t)srow * 256 + gch * 8;
  const size_t goff1 = (size_t)(srow + 64) * 256 + gch * 8;

  f32x4 acc[4][4] = {};

  const int fr = lane & 15;   // fragment row/col within 16
  const int kg = lane >> 4;   // k-group (8 contiguous k per lane)
  const int ckey = (fr >> 1) & 3;                 // read-side swizzle key
  const int rch = (kg ^ ckey) * 8;                // element offset of swizzled chunk

  for (int kt = 0; kt < 8; ++kt) {
    const int k0 = kt * 32;
    async16(Xa + goff0 + k0, (char*)ldsA + tid * 16);
    async16(Xa + goff1 + k0, (char*)ldsA + 4096 + tid * 16);
    async16(Xb + goff0 + k0, (char*)ldsB + tid * 16);
    async16(Xb + goff1 + k0, (char*)ldsB + 4096 + tid * 16);
    __syncthreads();   // compiler emits vmcnt(0) before s_barrier
    bf16x8 af[4], bfr[4];
    #pragma unroll
    for (int q = 0; q < 4; ++q) {
      af[q]  = *(const bf16x8*)(ldsA + (wr * 64 + q * 16 + fr) * 32 + rch);
      bfr[q] = *(const bf16x8*)(ldsB + (wc * 64 + q * 16 + fr) * 32 + rch);
    }
    #pragma unroll
    for (int ai = 0; ai < 4; ++ai)
      #pragma unroll
      for (int bj = 0; bj < 4; ++bj)
        acc[ai][bj] = __builtin_amdgcn_mfma_f32_16x16x32_bf16(af[ai], bfr[bj],
                                                              acc[ai][bj], 0, 0, 0);
    __syncthreads();
  }

  // epilogue: relu(1 - (sq_i + sq_j - 2*dot)), strict group mask, reduce
  const int ibase = r  * 128 + wr * 64;
  const int jbase = cb * 128 + wc * 64;
  const float* sqm = sq + m * 1024;

  float sqi[4][4];
  #pragma unroll
  for (int ai = 0; ai < 4; ++ai)
    #pragma unroll
    for (int rg = 0; rg < 4; ++rg)
      sqi[ai][rg] = sqm[ibase + ai * 16 + kg * 4 + rg];

  float local = 0.f;
  #pragma unroll
  for (int bj = 0; bj < 4; ++bj) {
    const int j = jbase + bj * 16 + fr;       // C/D: col = lane&15
    const float sqj = sqm[j];
    const int gj = j >> 2;
    #pragma unroll
    for (int ai = 0; ai < 4; ++ai) {
      #pragma unroll
      for (int rg = 0; rg < 4; ++rg) {
        const int i = ibase + ai * 16 + kg * 4 + rg;  // C/D: row = (lane>>4)*4 + reg
        const float d = sqi[ai][rg] + sqj - 2.f * acc[ai][bj][rg];
        const float v = 1.f - d;
        if (v > 0.f && gj > (i >> 2)) local += v;
      }
    }
  }
  #pragma unroll
  for (int off = 32; off; off >>= 1) local += __shfl_xor(local, off, 64);
  if (lane == 0) part[wid] = local;
  __syncthreads();
  if (tid == 0)
    heter_part[m * 36 + blockIdx.x] = part[0] + part[1] + part[2] + part[3];
}

// ---- Kernel 3: final reduction of partials + scaling (single block)
__global__ __launch_bounds__(256) void k_final(const float* __restrict__ homo_part,
                                               const float* __restrict__ heter_part,
                                               float* __restrict__ out) {
  __shared__ float red[8];
  const int tid = threadIdx.x;
  const int lane = tid & 63;
  const int wid = tid >> 6;

  float h = 0.f;
  for (int i = tid; i < 8192; i += 256) h += homo_part[i];
  #pragma unroll
  for (int off = 32; off; off >>= 1) h += __shfl_xor(h, off, 64);
  if (lane == 0) red[wid] = h;

  float e = 0.f;
  for (int i = tid; i < 1152; i += 256) e += heter_part[i];
  #pragma unroll
  for (int off = 32; off; off >>= 1) e += __shfl_xor(e, off, 64);
  if (lane == 0) red[4 + wid] = e;

  __syncthreads();
  if (tid == 0) out[0] = (red[0] + red[1] + red[2] + red[3]) * (1.0f / 1536.0f);
  if (tid == 1) out[1] = (red[4] + red[5] + red[6] + red[7]) * (1.0f / 522240.0f);
}

extern "C" void kernel_launch(void* const* d_in, const int* in_sizes, int n_in,
                              void* d_out, int out_size, void* d_ws, size_t ws_size,
                              hipStream_t stream) {
  const float* x = (const float*)d_in[0];
  float* out = (float*)d_out;
  char* ws = (char*)d_ws;
  unsigned short* xb = (unsigned short*)(ws + XB_OFF);
  float* sq         = (float*)(ws + SQ_OFF);
  float* homo_part  = (float*)(ws + HOMO_OFF);
  float* heter_part = (float*)(ws + HETER_OFF);

  k_fused<<<2048, 256, 0, stream>>>(x, xb, sq, homo_part);
  k_heter<<<dim3(36, 32), 256, 0, stream>>>(xb, sq, heter_part);
  k_final<<<1, 256, 0, stream>>>(homo_part, heter_part, out);
}

// Round 4
// 44.812 us; speedup vs baseline: 3.5157x; 1.0618x over previous
//
#include <hip/hip_runtime.h>
#include <stdint.h>

// MetricLoss: B=1024, M=32, F=256, K_GRP=4
// out[0] = (1/1536) * sum_{same-group pairs i<j, m} ||x_i,m - x_j,m||^2
// out[1] = (1/522240) * sum_{g_i<g_j, m} relu(1 - ||x_i,m - x_j,m||^2)
//
// ws layout:
//   [0,        16 MiB)   : xb  bf16 [32][1024][256]  (per-m contiguous matrices)
//   [16 MiB,  +128 KiB)  : sq  f32  [32][1024]
//   [+32 KiB]            : homo_part  f32 [8192]
//   [+4.5 KiB]           : heter_part f32 [1152]

typedef __attribute__((ext_vector_type(4))) float f32x4;
typedef __attribute__((ext_vector_type(8))) short bf16x8;

#define XB_OFF    0u
#define SQ_OFF    16777216u
#define HOMO_OFF  16908288u   // 8192 floats
#define HETER_OFF 16941056u   // 1152 floats

#define AS1 __attribute__((address_space(1)))
#define AS3 __attribute__((address_space(3)))

__device__ __forceinline__ void async16(const void* g, void* l) {
  __builtin_amdgcn_global_load_lds((const AS1 unsigned int*)(uintptr_t)g,
                                   (AS3 unsigned int*)(uintptr_t)l, 16, 0, 0);
}

__device__ __forceinline__ unsigned short f2bf(float f) {
  union { float f; unsigned u; } v; v.f = f;
  return (unsigned short)((v.u + 0x7fffu + ((v.u >> 16) & 1u)) >> 16);
}

// ---- Kernel 1 (fused convert + homo) — unchanged (HBM-BW-bound, ~8 us)
__global__ __launch_bounds__(256) void k_fused(const float* __restrict__ x,
                                               unsigned short* __restrict__ xb,
                                               float* __restrict__ sq,
                                               float* __restrict__ homo_part) {
  const int task = blockIdx.x * 4 + (threadIdx.x >> 6);  // task = g*32 + m
  const int lane = threadIdx.x & 63;
  const int g = task >> 5;
  const int m = task & 31;

  const float* base = x + ((size_t)(g * 4) * 32 + m) * 256 + lane * 4;
  float4 v[4];
  float sqv[4];
  #pragma unroll
  for (int a = 0; a < 4; ++a) {
    v[a] = *(const float4*)(base + a * 8192);
    float s = v[a].x * v[a].x + v[a].y * v[a].y + v[a].z * v[a].z + v[a].w * v[a].w;
    #pragma unroll
    for (int off = 32; off; off >>= 1) s += __shfl_xor(s, off, 64);
    sqv[a] = s;
    const int i = g * 4 + a;
    if (lane == 0) sq[m * 1024 + i] = s;
    ushort4 o;
    o.x = f2bf(v[a].x); o.y = f2bf(v[a].y); o.z = f2bf(v[a].z); o.w = f2bf(v[a].w);
    *(ushort4*)(xb + ((size_t)(m * 1024 + i)) * 256 + lane * 4) = o;
  }
  const float sx = v[0].x + v[1].x + v[2].x + v[3].x;
  const float sy = v[0].y + v[1].y + v[2].y + v[3].y;
  const float sz = v[0].z + v[1].z + v[2].z + v[3].z;
  const float sw = v[0].w + v[1].w + v[2].w + v[3].w;
  float s = sx * sx + sy * sy + sz * sz + sw * sw;
  #pragma unroll
  for (int off = 32; off; off >>= 1) s += __shfl_xor(s, off, 64);
  if (lane == 0)
    homo_part[task] = 4.f * (sqv[0] + sqv[1] + sqv[2] + sqv[3]) - s;
}

// Stage one 32 KB K-half of a 128x256 bf16 panel into LDS.
// LDS layout per half: [128 rows][16 chunks of 16B]; LDS chunk (r,c) holds
// global chunk c ^ (r&7) (row-XOR swizzle, both-sides-or-neither: linear
// gload_lds dest + swizzled per-lane global source + swizzled ds_read).
__device__ __forceinline__ void stage_half(const unsigned short* __restrict__ X,
                                           unsigned short* lds, int h, int tid) {
  #pragma unroll
  for (int i = 0; i < 8; ++i) {
    const int chunk = i * 256 + tid;        // 2048 chunks of 16B
    const int rr = chunk >> 4;
    const int c  = chunk & 15;
    const int gc = c ^ (rr & 7);
    async16(X + (size_t)rr * 256 + h * 128 + gc * 8,
            (char*)lds + h * 32768 + chunk * 16);
  }
}

// ---- Kernel 2: heter loss. Full-K(=256) LDS-resident 128x128 Gram tiles.
// 128 KB LDS -> 1 block/CU (OccupancyPercent will read low BY DESIGN).
// All loads issued upfront; two counted vmcnt waits; inner loop barrier-free.
__global__ __launch_bounds__(256) void k_heter(const unsigned short* __restrict__ xb,
                                               const float* __restrict__ sq,
                                               float* __restrict__ heter_part) {
  // XCD chunk swizzle: dispatch d -> work w so 144 consecutive works (4 m's,
  // 2 MB panel set, fits one XCD's 4 MB L2) land on one XCD (d%8 heuristic).
  const int d = blockIdx.x;                  // 1152 = 8 * 144
  const int w = (d & 7) * 144 + (d >> 3);
  const int m = w / 36;
  int t = w - m * 36, r = 0;                 // 36 tiles: (r,c), c>=r
  while (t >= 8 - r) { t -= 8 - r; ++r; }
  const int cb = r + t;
  const bool diag = (cb == r);

  __shared__ __align__(16) unsigned short ldsA[32768];   // 64 KB, 2 K-halves
  __shared__ __align__(16) unsigned short ldsB[32768];   // 64 KB
  __shared__ float part[4];

  const int tid = threadIdx.x;
  const int lane = tid & 63;
  const int wid = tid >> 6;
  const int wr = wid >> 1, wc = wid & 1;     // 2x2 waves, each 64x64 output

  const unsigned short* Xa = xb + ((size_t)m * 1024 + r  * 128) * 256;
  const unsigned short* Xb = xb + ((size_t)m * 1024 + cb * 128) * 256;

  // Issue ALL staging upfront (32 loads/thread off-diag, 16 on diag).
  if (diag) {
    stage_half(Xa, ldsA, 0, tid);
    stage_half(Xa, ldsA, 1, tid);
  } else {
    stage_half(Xa, ldsA, 0, tid);
    stage_half(Xb, ldsB, 0, tid);
    stage_half(Xa, ldsA, 1, tid);
    stage_half(Xb, ldsB, 1, tid);
  }

  const int fr = lane & 15;    // fragment row within 16
  const int kg = lane >> 4;    // k-group (8 contiguous k per lane)
  const unsigned short* ldsBb = diag ? ldsA : ldsB;

  f32x4 acc[4][4] = {};

  // wait for K-half-0 only (counted: half-1 loads stay in flight), sync, compute
  if (diag) { asm volatile("s_waitcnt vmcnt(8)" ::: "memory"); }
  else      { asm volatile("s_waitcnt vmcnt(16)" ::: "memory"); }
  __builtin_amdgcn_s_barrier();
  asm volatile("" ::: "memory");

  #pragma unroll
  for (int h = 0; h < 2; ++h) {
    if (h == 1) {   // half-1: drain remaining loads (latency hidden under half-0)
      asm volatile("s_waitcnt vmcnt(0)" ::: "memory");
      __builtin_amdgcn_s_barrier();
      asm volatile("" ::: "memory");
    }
    const unsigned short* lA = ldsA + h * 16384;
    const unsigned short* lB = ldsBb + h * 16384;
    #pragma unroll
    for (int kk = 0; kk < 4; ++kk) {
      bf16x8 af[4], bv[4];
      #pragma unroll
      for (int q = 0; q < 4; ++q) {
        const int ra = wr * 64 + q * 16 + fr;
        const int ca = ((kk << 2) + kg) ^ (ra & 7);
        af[q] = *(const bf16x8*)(lA + ra * 128 + ca * 8);
        const int rb = wc * 64 + q * 16 + fr;
        const int cbx = ((kk << 2) + kg) ^ (rb & 7);
        bv[q] = *(const bf16x8*)(lB + rb * 128 + cbx * 8);
      }
      #pragma unroll
      for (int ai = 0; ai < 4; ++ai)
        #pragma unroll
        for (int bj = 0; bj < 4; ++bj)
          acc[ai][bj] = __builtin_amdgcn_mfma_f32_16x16x32_bf16(af[ai], bv[bj],
                                                                acc[ai][bj], 0, 0, 0);
    }
  }

  // epilogue: relu(1 - (sq_i + sq_j - 2*dot)), strict group mask, reduce
  const int ibase = r  * 128 + wr * 64;
  const int jbase = cb * 128 + wc * 64;
  const float* sqm = sq + m * 1024;

  float sqi[4][4];
  #pragma unroll
  for (int ai = 0; ai < 4; ++ai)
    #pragma unroll
    for (int rg = 0; rg < 4; ++rg)
      sqi[ai][rg] = sqm[ibase + ai * 16 + kg * 4 + rg];

  float local = 0.f;
  #pragma unroll
  for (int bj = 0; bj < 4; ++bj) {
    const int j = jbase + bj * 16 + fr;       // C/D: col = lane&15
    const float sqj = sqm[j];
    const int gj = j >> 2;
    #pragma unroll
    for (int ai = 0; ai < 4; ++ai) {
      #pragma unroll
      for (int rg = 0; rg < 4; ++rg) {
        const int i = ibase + ai * 16 + kg * 4 + rg;  // C/D: row = (lane>>4)*4 + reg
        const float dd = sqi[ai][rg] + sqj - 2.f * acc[ai][bj][rg];
        const float v = 1.f - dd;
        if (v > 0.f && gj > (i >> 2)) local += v;
      }
    }
  }
  #pragma unroll
  for (int off = 32; off; off >>= 1) local += __shfl_xor(local, off, 64);
  if (lane == 0) part[wid] = local;
  __syncthreads();
  if (tid == 0)
    heter_part[m * 36 + (w - m * 36)] = part[0] + part[1] + part[2] + part[3];
}

// ---- Kernel 3: final reduction of partials + scaling (single block)
__global__ __launch_bounds__(256) void k_final(const float* __restrict__ homo_part,
                                               const float* __restrict__ heter_part,
                                               float* __restrict__ out) {
  __shared__ float red[8];
  const int tid = threadIdx.x;
  const int lane = tid & 63;
  const int wid = tid >> 6;

  float h = 0.f;
  for (int i = tid; i < 8192; i += 256) h += homo_part[i];
  #pragma unroll
  for (int off = 32; off; off >>= 1) h += __shfl_xor(h, off, 64);
  if (lane == 0) red[wid] = h;

  float e = 0.f;
  for (int i = tid; i < 1152; i += 256) e += heter_part[i];
  #pragma unroll
  for (int off = 32; off; off >>= 1) e += __shfl_xor(e, off, 64);
  if (lane == 0) red[4 + wid] = e;

  __syncthreads();
  if (tid == 0) out[0] = (red[0] + red[1] + red[2] + red[3]) * (1.0f / 1536.0f);
  if (tid == 1) out[1] = (red[4] + red[5] + red[6] + red[7]) * (1.0f / 522240.0f);
}

extern "C" void kernel_launch(void* const* d_in, const int* in_sizes, int n_in,
                              void* d_out, int out_size, void* d_ws, size_t ws_size,
                              hipStream_t stream) {
  const float* x = (const float*)d_in[0];
  float* out = (float*)d_out;
  char* ws = (char*)d_ws;
  unsigned short* xb = (unsigned short*)(ws + XB_OFF);
  float* sq         = (float*)(ws + SQ_OFF);
  float* homo_part  = (float*)(ws + HOMO_OFF);
  float* heter_part = (float*)(ws + HETER_OFF);

  k_fused<<<2048, 256, 0, stream>>>(x, xb, sq, homo_part);
  k_heter<<<1152, 256, 0, stream>>>(xb, sq, heter_part);
  k_final<<<1, 256, 0, stream>>>(homo_part, heter_part, out);
}